// Round 5
// baseline (139.844 us; speedup 1.0000x reference)
//
#include <hip/hip_runtime.h>

// Xonv2D: per-location conv. B=32, CIN=16, H=W=64, COUT=32, K=3, pad=1.
// out[b,o,h,w] = sum_{c,kh,kw} x[b,c,h+kh-1,w+kw-1] * W[h,w,o,c,kh,kw] + bias[h,w,o]
//
// R11 = R6 + NONTEMPORAL weight loads (the only diff: 3 load sites use
// __builtin_nontemporal_load -> global_load_dwordx4 ... nt).
//
// Evidence so far: depth-4 prefetch was NEUTRAL vs depth-2 (harness 124.3 vs
// 124.1 us) -> per-wave read depth is not binding. Observed weight-stream rate
// ~2.8 TB/s matches a per-CU miss-concurrency wall: 64 lines x 64B / 900cy
// = 4.55 B/cy/CU x 256 CU = 2.79 TB/s, while harness fills sustain 6.6 TB/s
// writes. Theory: the wall is the L1/TCP miss queue; weights are read-once so
// L1 allocation is pure loss. nt loads change the allocation/tracking path.
// Predict: if L1-MSHR-limited, kernel ~36.5 -> ~26-30us, harness -> ~114-118.
// If neutral -> cap is L2/DRAM-side read concurrency; near-roofline for this
// structure (next: depth-9 full preload to overlap prologue, or stop).

#define CIN  16
#define HW_  4096            // H*W
#define PP   144             // CIN*3*3
#define RST  20              // hw per (b, c*3+r) row: slot = col - w0 + 2
#define BST  962             // hw per b: 48*20 + 2 pad (dw stride 481 == 1 mod 32)

typedef float v4f  __attribute__((ext_vector_type(4)));
typedef float v16f __attribute__((ext_vector_type(16)));
typedef short v8s  __attribute__((ext_vector_type(8)));

__device__ __forceinline__ unsigned short f2bf(float f) {
    unsigned int u = __builtin_bit_cast(unsigned int, f);
    u += 0x7fffu + ((u >> 16) & 1u);          // RNE
    return (unsigned short)(u >> 16);
}
__device__ __forceinline__ unsigned int pk2(float a, float b) {
    return (unsigned int)f2bf(a) | ((unsigned int)f2bf(b) << 16);
}
__device__ __forceinline__ constexpr int offp(int p) {
    // p = c*9 + r*3 + kw  ->  LDS hw offset (row part + kw + 1)
    const int c = p / 9, rem = p % 9, r = rem / 3, kw = rem % 3;
    return (c * 3 + r) * RST + kw + 1;
}

__global__ __launch_bounds__(1024, 4) void xonv_kernel(
    const float* __restrict__ x,
    const float* __restrict__ wt,
    const float* __restrict__ bias,
    float* __restrict__ out)
{
    const int t  = threadIdx.x;
    const int bi = blockIdx.x;                 // 0..255
    // XCD swizzle: bi&7 = h&7 -> all 4 w-groups of a row on one XCD.
    const int h  = ((bi >> 5) << 3) + (bi & 7);
    const int wg = (bi >> 3) & 3;
    const int w0 = wg << 4;

    __shared__ unsigned short xs[32 * BST];    // 61,568 B
    float* ol = (float*)xs;                    // epilogue alias (34,816 B)

    const int l  = t & 63;
    const int wv = t >> 6;                     // wave = location 0..15
    const int w  = w0 + wv;
    const int o  = l & 31;                     // out-channel col / batch lane idx
    const int kh = l >> 5;                     // k-half (0/1)

    // ---- weight slice pointers; depth-4 rotating prefetch, NT loads -------
    const float* wp = wt + (size_t)(h * 64 + w) * (32 * PP)
                         + (size_t)o * PP + kh * 8;
    v4f ca[4], cb[4];
#pragma unroll
    for (int s = 0; s < 4; ++s) {
        ca[s] = __builtin_nontemporal_load((const v4f*)(wp + s * 16));
        cb[s] = __builtin_nontemporal_load((const v4f*)(wp + s * 16 + 4));
    }
    const float bia = bias[(size_t)(h * 64 + w) * 32 + o];

    // ---------------- stage x windows: 1536 rows x 6 float4 ----------------
    // job j: rid = j/6 (row = b*48 + c*3 + r), sub = j%6; window col w0-4+sub*4
    const int wstart = w0 - 4;
#pragma unroll
    for (int i = 0; i < 9; ++i) {
        const int j   = t + i * 1024;
        const int rid = (int)(((unsigned)j * 43691u) >> 18);   // j/6
        const int sub = j - rid * 6;
        const int b   = (rid * 683) >> 15;                     // rid/48
        const int cr  = rid - b * 48;
        const int c   = (cr * 43) >> 7;                        // cr/3
        const int r   = cr - c * 3;
        const int row = h + r - 1;
        const int col4 = wstart + sub * 4;
        float4 f = {0.f, 0.f, 0.f, 0.f};
        if ((unsigned)row < 64u && (unsigned)col4 <= 60u)
            f = *(const float4*)(x + ((size_t)(b * CIN + c)) * HW_
                                   + row * 64 + col4);
        unsigned short* dst = xs + b * BST + cr * RST;
        if (sub == 0) {
            ((unsigned int*)dst)[0] = pk2(f.z, f.w);           // slots 0,1
        } else if (sub == 5) {
            ((unsigned int*)dst)[9] = pk2(f.x, f.y);           // slots 18,19
        } else {
            unsigned int* d = (unsigned int*)(dst + sub * 4 - 2);
            d[0] = pk2(f.x, f.y);                              // slots 4s-2..
            d[1] = pk2(f.z, f.w);
        }
    }
    __syncthreads();

    // ---------------- compute: one wave per location, 9 x 32x32x16 ---------
    const int gb = o * BST + wv;               // per-lane gather base (hw)

    v16f acc;
#pragma unroll
    for (int i = 0; i < 16; ++i) acc[i] = 0.f;

#pragma unroll
    for (int kc = 0; kc < 9; ++kc) {
        const int slot = kc & 3;

        // pack B-frag from the slice loaded 4 iterations ago
        union { unsigned int u[4]; v8s s; } ub;
        ub.u[0] = pk2(ca[slot].x, ca[slot].y);
        ub.u[1] = pk2(ca[slot].z, ca[slot].w);
        ub.u[2] = pk2(cb[slot].x, cb[slot].y);
        ub.u[3] = pk2(cb[slot].z, cb[slot].w);

        // refill the slot with slice kc+4 (keeps 4 slices in flight)
        if (kc + 4 < 9) {
            ca[slot] = __builtin_nontemporal_load(
                           (const v4f*)(wp + (kc + 4) * 16));
            cb[slot] = __builtin_nontemporal_load(
                           (const v4f*)(wp + (kc + 4) * 16 + 4));
        }

        v8s a;
#pragma unroll
        for (int j = 0; j < 8; ++j) {
            const int C0 = offp(kc * 16 + j);        // compile-time
            const int C1 = offp(kc * 16 + 8 + j);    // compile-time
            a[j] = (short)xs[gb + (kh ? C1 : C0)];
        }

        acc = __builtin_amdgcn_mfma_f32_32x32x16_bf16(a, ub.s, acc, 0, 0, 0);
    }

    __syncthreads();   // all xs gathers done; reuse LDS as ol[512][17]

    // ---------------- epilogue: two b-halves, full-line stores -------------
#pragma unroll
    for (int half = 0; half < 2; ++half) {
#pragma unroll
        for (int rr = 0; rr < 8; ++rr) {
            const int r     = half * 8 + rr;
            const int browl = (r & 3) + 8 * ((r >> 2) & 1) + 4 * kh;  // 0..15
            ol[(browl * 32 + o) * 17 + wv] = acc[r] + bia;
        }
        __syncthreads();
#pragma unroll
        for (int i2 = 0; i2 < 2; ++i2) {
            const int flat = t + i2 * 1024;
            const int bol  = flat >> 2;            // 0..511 : browl*32+o
            const int q4   = flat & 3;
            const int base = bol * 17 + q4 * 4;
            float4 v;
            v.x = ol[base + 0]; v.y = ol[base + 1];
            v.z = ol[base + 2]; v.w = ol[base + 3];
            const int bg = half * 16 + (bol >> 5);         // batch
            const int og = bol & 31;                       // out-channel
            *(float4*)(out + ((size_t)(bg * 32 + og)) * HW_
                           + h * 64 + w0 + q4 * 4) = v;
        }
        __syncthreads();
    }
}

extern "C" void kernel_launch(void* const* d_in, const int* in_sizes, int n_in,
                              void* d_out, int out_size, void* d_ws, size_t ws_size,
                              hipStream_t stream) {
    const float* x       = (const float*)d_in[0];
    const float* weights = (const float*)d_in[1];
    const float* bias    = (const float*)d_in[2];
    float* out           = (float*)d_out;
    (void)in_sizes; (void)n_in; (void)out_size; (void)d_ws; (void)ws_size;

    dim3 grid(256);     // 64 h x 4 w-groups, XCD-swizzled
    dim3 block(1024);   // 16 waves = 16 w-locations
    hipLaunchKernelGGL(xonv_kernel, grid, block, 0, stream, x, weights, bias, out);
}

// Round 7
// 130.700 us; speedup vs baseline: 1.0700x; 1.0700x over previous
//
#include <hip/hip_runtime.h>

// Xonv2D: per-location conv. B=32, CIN=16, H=W=64, COUT=32, K=3, pad=1.
// out[b,o,h,w] = sum_{c,kh,kw} x[b,c,h+kh-1,w+kw-1] * W[h,w,o,c,kh,kw] + bias[h,w,o]
//
// R12: SEQUENTIAL weight streaming through LDS (replaces per-lane strided
// register loads). Evidence: depth-4 prefetch neutral (124.3 vs 124.1us);
// nt loads REGRESSED +15.5us (lost L1/MSHR merging of the 4 requests per
// weight line -> ~4608 extra line services/CU). Revised theory: the 2.8 TB/s
// weight wall is DRAM/row-locality inefficiency of 32-lines-@-576B-stride
// instructions x ~4096 interleaved streams, NOT per-wave depth (copy ubench
// does 24.6 GB/s/CU sequential vs our 11). Fix: per 18KB location chunk, all
// 1024 threads read contiguous float4s in address order, convert bf16, stage
// to LDS (o-stride padded to 304B), wave j pulls fragments for its MFMAs.
// 16 phases, 2 LDS buffers, loads 2 phases ahead. x-path/epilogue unchanged.
// Predict: weight drain 27->12-14us, kernel ~36.5->~21-26, harness ~108-114.
// Null => hard per-CU line-concurrency wall (roofline). nt = rejected lever.
//
// [R13 resubmission: R12 round hit GPUAcquisitionTimeout -- no data.
//  Identical kernel; re-audited fragment equivalence, magic-div decode,
//  barrier/race structure, LDS budget (81,024B) while waiting.]

#define CIN  16
#define HW_  4096            // H*W
#define PP   144             // CIN*3*3 floats per (loc, o)
#define RST  20              // hw per (b, c*3+r) row: slot = col - w0 + 2
#define BST  962             // hw per b: 48*20 + 2 pad (dw stride 481 == 1 mod 32)
#define LOCF 4608            // floats per location = 32*PP
#define WPAD 152             // u16 per o-stripe in wlds (304B, 16B-aligned pad)
#define WBUF 4864            // u16 per chunk buffer = 32*WPAD (9,728B)

typedef float v4f  __attribute__((ext_vector_type(4)));
typedef float v16f __attribute__((ext_vector_type(16)));
typedef short v8s  __attribute__((ext_vector_type(8)));

__device__ __forceinline__ unsigned short f2bf(float f) {
    unsigned int u = __builtin_bit_cast(unsigned int, f);
    u += 0x7fffu + ((u >> 16) & 1u);          // RNE
    return (unsigned short)(u >> 16);
}
__device__ __forceinline__ unsigned int pk2(float a, float b) {
    return (unsigned int)f2bf(a) | ((unsigned int)f2bf(b) << 16);
}
__device__ __forceinline__ constexpr int offp(int p) {
    // p = c*9 + r*3 + kw  ->  LDS hw offset (row part + kw + 1)
    const int c = p / 9, rem = p % 9, r = rem / 3, kw = rem % 3;
    return (c * 3 + r) * RST + kw + 1;
}

__global__ __launch_bounds__(1024, 4) void xonv_kernel(
    const float* __restrict__ x,
    const float* __restrict__ wt,
    const float* __restrict__ bias,
    float* __restrict__ out)
{
    const int t  = threadIdx.x;
    const int bi = blockIdx.x;                 // 0..255
    // XCD swizzle: bi&7 = h&7 -> all 4 w-groups of a row on one XCD.
    const int h  = ((bi >> 5) << 3) + (bi & 7);
    const int wg = (bi >> 3) & 3;
    const int w0 = wg << 4;

    __shared__ unsigned short xs[32 * BST];    // 61,568 B
    __shared__ unsigned short wlds[2 * WBUF];  // 19,456 B  (total 81,024 B)
    float* ol = (float*)xs;                    // epilogue alias (34,816 B)

    const int l  = t & 63;
    const int wv = t >> 6;                     // wave = location 0..15
    const int w  = w0 + wv;
    const int o  = l & 31;                     // out-channel col / batch lane idx
    const int kh = l >> 5;                     // k-half (0/1)

    // ---- per-thread weight stage-job decode (identical every phase) -------
    // chunk = one location's 18,432B = 1152 float4 jobs; thread t does job t,
    // and job 1024+t for t<128. o = q/36 (magic 1821), rem = q%36.
    const int q0  = t;
    const int o0  = (q0 * 1821) >> 16;
    const int r0  = q0 - o0 * 36;
    const int q1  = t + 1024;
    const int o1  = (q1 * 1821) >> 16;
    const int r1  = q1 - o1 * 36;
    const bool j2 = (t < 128);

    const float* wbase = wt + (size_t)(h * 64 + w0) * LOCF;

    // ---- pre-loop: issue chunk0 -> regs A, chunk1 -> regs B (sequential) --
    v4f a0A = *(const v4f*)(wbase + 0 * LOCF + q0 * 4);
    v4f a1A = {0.f, 0.f, 0.f, 0.f};
    if (j2) a1A = *(const v4f*)(wbase + 0 * LOCF + q1 * 4);
    v4f a0B = *(const v4f*)(wbase + 1 * LOCF + q0 * 4);
    v4f a1B = {0.f, 0.f, 0.f, 0.f};
    if (j2) a1B = *(const v4f*)(wbase + 1 * LOCF + q1 * 4);

    const float bia = bias[(size_t)(h * 64 + w) * 32 + o];

    // ---------------- stage x windows: 1536 rows x 6 float4 ----------------
    // (unchanged; its work covers chunk0/1 load latency)
    const int wstart = w0 - 4;
#pragma unroll
    for (int i = 0; i < 9; ++i) {
        const int j   = t + i * 1024;
        const int rid = (int)(((unsigned)j * 43691u) >> 18);   // j/6
        const int sub = j - rid * 6;
        const int b   = (rid * 683) >> 15;                     // rid/48
        const int cr  = rid - b * 48;
        const int c   = (cr * 43) >> 7;                        // cr/3
        const int r   = cr - c * 3;
        const int row = h + r - 1;
        const int col4 = wstart + sub * 4;
        float4 f = {0.f, 0.f, 0.f, 0.f};
        if ((unsigned)row < 64u && (unsigned)col4 <= 60u)
            f = *(const float4*)(x + ((size_t)(b * CIN + c)) * HW_
                                   + row * 64 + col4);
        unsigned short* dst = xs + b * BST + cr * RST;
        if (sub == 0) {
            ((unsigned int*)dst)[0] = pk2(f.z, f.w);           // slots 0,1
        } else if (sub == 5) {
            ((unsigned int*)dst)[9] = pk2(f.x, f.y);           // slots 18,19
        } else {
            unsigned int* d = (unsigned int*)(dst + sub * 4 - 2);
            d[0] = pk2(f.x, f.y);                              // slots 4s-2..
            d[1] = pk2(f.z, f.w);
        }
    }

    // ---- write chunk0 (regs A) into buf0: u16 idx = o*152 + f_in_o --------
    {
        unsigned int* wb = (unsigned int*)wlds;                // buf 0
        wb[o0 * 76 + r0 * 2]     = pk2(a0A.x, a0A.y);
        wb[o0 * 76 + r0 * 2 + 1] = pk2(a0A.z, a0A.w);
        if (j2) {
            wb[o1 * 76 + r1 * 2]     = pk2(a1A.x, a1A.y);
            wb[o1 * 76 + r1 * 2 + 1] = pk2(a1A.z, a1A.w);
        }
    }
    __syncthreads();                       // xs + wbuf0 ready

    const int gb = o * BST + wv;           // per-lane xs gather base (hw)

    v16f acc;
#pragma unroll
    for (int i = 0; i < 16; ++i) acc[i] = 0.f;

    // ---- 16 phases: issue c(J+2) | write c(J+1) | wave J computes cJ ------
    // B-fragment from LDS: u16 idx o*152 + kc*16 + kh*8 == floats
    // [o*144 + kc*16 + kh*8 .. +8) in memory order == old ub.s exactly.
#define PHASE(J, RA0, RA1, RB0, RB1)                                           \
    {                                                                          \
        if ((J) + 2 < 16) {                                                    \
            RA0 = *(const v4f*)(wbase + ((J) + 2) * LOCF + q0 * 4);            \
            if (j2) RA1 = *(const v4f*)(wbase + ((J) + 2) * LOCF + q1 * 4);    \
        }                                                                      \
        if ((J) + 1 < 16) {                                                    \
            unsigned int* wb = (unsigned int*)&wlds[(((J) + 1) & 1) * WBUF];   \
            wb[o0 * 76 + r0 * 2]     = pk2(RB0.x, RB0.y);                      \
            wb[o0 * 76 + r0 * 2 + 1] = pk2(RB0.z, RB0.w);                      \
            if (j2) {                                                          \
                wb[o1 * 76 + r1 * 2]     = pk2(RB1.x, RB1.y);                  \
                wb[o1 * 76 + r1 * 2 + 1] = pk2(RB1.z, RB1.w);                  \
            }                                                                  \
        }                                                                      \
        if (wv == (J)) {                                                       \
            const unsigned short* wfr =                                        \
                &wlds[((J) & 1) * WBUF + o * WPAD + kh * 8];                   \
            _Pragma("unroll")                                                  \
            for (int kc = 0; kc < 9; ++kc) {                                   \
                v8s bs = *(const v8s*)(wfr + kc * 16);                         \
                v8s a;                                                         \
                _Pragma("unroll")                                              \
                for (int jj = 0; jj < 8; ++jj) {                               \
                    const int C0 = offp(kc * 16 + jj);                         \
                    const int C1 = offp(kc * 16 + 8 + jj);                     \
                    a[jj] = (short)xs[gb + (kh ? C1 : C0)];                    \
                }                                                              \
                acc = __builtin_amdgcn_mfma_f32_32x32x16_bf16(a, bs, acc,      \
                                                              0, 0, 0);        \
            }                                                                  \
        }                                                                      \
        __syncthreads();                                                       \
    }

    PHASE(0,  a0A, a1A, a0B, a1B)
    PHASE(1,  a0B, a1B, a0A, a1A)
    PHASE(2,  a0A, a1A, a0B, a1B)
    PHASE(3,  a0B, a1B, a0A, a1A)
    PHASE(4,  a0A, a1A, a0B, a1B)
    PHASE(5,  a0B, a1B, a0A, a1A)
    PHASE(6,  a0A, a1A, a0B, a1B)
    PHASE(7,  a0B, a1B, a0A, a1A)
    PHASE(8,  a0A, a1A, a0B, a1B)
    PHASE(9,  a0B, a1B, a0A, a1A)
    PHASE(10, a0A, a1A, a0B, a1B)
    PHASE(11, a0B, a1B, a0A, a1A)
    PHASE(12, a0A, a1A, a0B, a1B)
    PHASE(13, a0B, a1B, a0A, a1A)
    PHASE(14, a0A, a1A, a0B, a1B)
    PHASE(15, a0B, a1B, a0A, a1A)
#undef PHASE
    // final phase barrier doubles as the pre-epilogue sync (xs gathers done)

    // ---------------- epilogue: two b-halves, full-line stores -------------
#pragma unroll
    for (int half = 0; half < 2; ++half) {
#pragma unroll
        for (int rr = 0; rr < 8; ++rr) {
            const int r     = half * 8 + rr;
            const int browl = (r & 3) + 8 * ((r >> 2) & 1) + 4 * kh;  // 0..15
            ol[(browl * 32 + o) * 17 + wv] = acc[r] + bia;
        }
        __syncthreads();
#pragma unroll
        for (int i2 = 0; i2 < 2; ++i2) {
            const int flat = t + i2 * 1024;
            const int bol  = flat >> 2;            // 0..511 : browl*32+o
            const int q4   = flat & 3;
            const int base = bol * 17 + q4 * 4;
            float4 v;
            v.x = ol[base + 0]; v.y = ol[base + 1];
            v.z = ol[base + 2]; v.w = ol[base + 3];
            const int bg = half * 16 + (bol >> 5);         // batch
            const int og = bol & 31;                       // out-channel
            *(float4*)(out + ((size_t)(bg * 32 + og)) * HW_
                           + h * 64 + w0 + q4 * 4) = v;
        }
        __syncthreads();
    }
}

extern "C" void kernel_launch(void* const* d_in, const int* in_sizes, int n_in,
                              void* d_out, int out_size, void* d_ws, size_t ws_size,
                              hipStream_t stream) {
    const float* x       = (const float*)d_in[0];
    const float* weights = (const float*)d_in[1];
    const float* bias    = (const float*)d_in[2];
    float* out           = (float*)d_out;
    (void)in_sizes; (void)n_in; (void)out_size; (void)d_ws; (void)ws_size;

    dim3 grid(256);     // 64 h x 4 w-groups, XCD-swizzled
    dim3 block(1024);   // 16 waves = 16 w-locations
    hipLaunchKernelGGL(xonv_kernel, grid, block, 0, stream, x, weights, bias, out);
}

// Round 8
// 128.258 us; speedup vs baseline: 1.0903x; 1.0190x over previous
//
#include <hip/hip_runtime.h>

// Xonv2D: per-location conv. B=32, CIN=16, H=W=64, COUT=32, K=3, pad=1.
// out[b,o,h,w] = sum_{c,kh,kw} x[b,c,h+kh-1,w+kw-1] * W[h,w,o,c,kh,kw] + bias[h,w,o]
//
// R14: 2 blocks/CU restructure. Evidence ledger:
//   depth-4 prefetch: NEUTRAL (124.1 vs 124.3) -> per-wave depth not binding
//   nt weight loads:  -15.5us REGRESSION      -> L1 merging of 4 req/line real
//   R12 seq-via-serial-phases: kernel 49 vs 42.8us, ALL pipes idle (MFMA 0.8%,
//     VALU 14%, BW 17%, occ 39%) -> serialization confound; ordering untested
//     and unfixable without staging. FETCH=48.6MB shows partial LLC retention;
//     fabric bytes 67.7MB -> ~10us floor at fill-rate 6.6TB/s.
// This round: revert weight path to R4 register rotation (depth-2), split the
// single 1024-thread block into two independent 512-thread blocks per CU
// (512 blocks x 8 waves, 8 locations each; LDS 37KB; launch_bounds(512,4)).
// Mechanism: block B's load-heavy prologue overlaps block A's compute/epilogue
// dry spells -> memory pipe stays fed at equal waves/CU.
// Predict: overlap real -> kernel ~30-36us, harness ~112-118.
//          per-CU MSHR wall -> null (~124-126) -> third null -> roofline.

#define CIN  16
#define HW_  4096            // H*W
#define PP   144             // CIN*3*3
#define RST  12              // hw per (b, c*3+r) row: slot = col - w0 + 2 (10+2 pad)
#define BST  578             // hw per b: 48*12 + 2 pad (dw stride 289 == 1 mod 32)

typedef float v16f __attribute__((ext_vector_type(16)));
typedef short v8s  __attribute__((ext_vector_type(8)));

__device__ __forceinline__ unsigned short f2bf(float f) {
    unsigned int u = __builtin_bit_cast(unsigned int, f);
    u += 0x7fffu + ((u >> 16) & 1u);          // RNE
    return (unsigned short)(u >> 16);
}
__device__ __forceinline__ unsigned int pk2(float a, float b) {
    return (unsigned int)f2bf(a) | ((unsigned int)f2bf(b) << 16);
}
__device__ __forceinline__ constexpr int offp(int p) {
    // p = c*9 + r*3 + kw  ->  LDS hw offset (row part + kw + 1)
    const int c = p / 9, rem = p % 9, r = rem / 3, kw = rem % 3;
    return (c * 3 + r) * RST + kw + 1;
}

__global__ __launch_bounds__(512, 4) void xonv_kernel(
    const float* __restrict__ x,
    const float* __restrict__ wt,
    const float* __restrict__ bias,
    float* __restrict__ out)
{
    const int t  = threadIdx.x;
    const int bi = blockIdx.x;                 // 0..511
    // bits: [0:2]=h&7 (XCD id), [3:5]=w-group, [6:8]=h-high.
    // All 8 w-groups of a row land on one XCD -> x rows shared in that L2.
    const int h  = ((bi >> 6) << 3) + (bi & 7);
    const int wg = (bi >> 3) & 7;
    const int w0 = wg << 3;

    __shared__ unsigned short xs[32 * BST];    // 36,992 B (2 blocks/CU fit)
    float* ol = (float*)xs;                    // epilogue alias (18,432 B)

    const int l  = t & 63;
    const int wv = t >> 6;                     // wave = location 0..7
    const int w  = w0 + wv;
    const int o  = l & 31;                     // out-channel col / batch lane idx
    const int kh = l >> 5;                     // k-half (0/1)

    // ---- weight slice pointers; depth-2 rotating prefetch (R4 form) -------
    const float* wp = wt + (size_t)(h * 64 + w) * (32 * PP)
                         + (size_t)o * PP + kh * 8;
    float4 ca[2], cb[2];
    ca[0] = *(const float4*)(wp);
    cb[0] = *(const float4*)(wp + 4);
    ca[1] = *(const float4*)(wp + 16);
    cb[1] = *(const float4*)(wp + 20);
    const float bia = bias[(size_t)(h * 64 + w) * 32 + o];

    // ---------------- stage x windows: 1536 rows x 4 float4 ----------------
    // job j: rid = j>>2 (row = b*48 + c*3 + r), sub = j&3; window col w0-4+sub*4
    const int wstart = w0 - 4;
#pragma unroll
    for (int i = 0; i < 12; ++i) {
        const int j   = t + i * 512;
        const int rid = j >> 2;
        const int sub = j & 3;
        const int b   = (rid * 683) >> 15;                     // rid/48
        const int cr  = rid - b * 48;
        const int c   = (cr * 43) >> 7;                        // cr/3
        const int r   = cr - c * 3;
        const int row = h + r - 1;
        const int col4 = wstart + sub * 4;
        float4 f = {0.f, 0.f, 0.f, 0.f};
        if ((unsigned)row < 64u && (unsigned)col4 <= 60u)
            f = *(const float4*)(x + ((size_t)(b * CIN + c)) * HW_
                                   + row * 64 + col4);
        unsigned short* dst = xs + b * BST + cr * RST;
        if (sub == 0) {
            ((unsigned int*)dst)[0] = pk2(f.z, f.w);           // slots 0,1
        } else if (sub == 3) {
            ((unsigned int*)dst)[5] = pk2(f.x, f.y);           // slots 10,11
        } else {
            unsigned int* d = (unsigned int*)dst + (sub * 2 - 1);
            d[0] = pk2(f.x, f.y);                              // slots 4s-2..
            d[1] = pk2(f.z, f.w);
        }
    }
    __syncthreads();

    // ---------------- compute: one wave per location, 9 x 32x32x16 ---------
    const int gb = o * BST + wv;               // per-lane gather base (hw)

    v16f acc;
#pragma unroll
    for (int i = 0; i < 16; ++i) acc[i] = 0.f;

#pragma unroll
    for (int kc = 0; kc < 9; ++kc) {
        const int slot = kc & 1;

        // pack B-frag from the slice loaded 2 iterations ago
        union { unsigned int u[4]; v8s s; } ub;
        ub.u[0] = pk2(ca[slot].x, ca[slot].y);
        ub.u[1] = pk2(ca[slot].z, ca[slot].w);
        ub.u[2] = pk2(cb[slot].x, cb[slot].y);
        ub.u[3] = pk2(cb[slot].z, cb[slot].w);

        // refill the slot with slice kc+2 (keeps 2 slices in flight)
        if (kc + 2 < 9) {
            ca[slot] = *(const float4*)(wp + (kc + 2) * 16);
            cb[slot] = *(const float4*)(wp + (kc + 2) * 16 + 4);
        }

        v8s a;
#pragma unroll
        for (int jj = 0; jj < 8; ++jj) {
            const int C0 = offp(kc * 16 + jj);        // compile-time
            const int C1 = offp(kc * 16 + 8 + jj);    // compile-time
            a[jj] = (short)xs[gb + (kh ? C1 : C0)];
        }

        acc = __builtin_amdgcn_mfma_f32_32x32x16_bf16(a, ub.s, acc, 0, 0, 0);
    }

    __syncthreads();   // all xs gathers done; reuse LDS as ol[512][9]

    // ---------------- epilogue: two b-halves, 2x float4 per row ------------
#pragma unroll
    for (int half = 0; half < 2; ++half) {
#pragma unroll
        for (int rr = 0; rr < 8; ++rr) {
            const int r     = half * 8 + rr;
            const int browl = (r & 3) + 8 * ((r >> 2) & 1) + 4 * kh;  // 0..15
            ol[(browl * 32 + o) * 9 + wv] = acc[r] + bia;
        }
        __syncthreads();
#pragma unroll
        for (int i2 = 0; i2 < 2; ++i2) {
            const int flat = t + i2 * 512;         // 0..1023
            const int bol  = flat >> 1;            // 0..511 : browl*32+o
            const int q4   = flat & 1;
            const int base = bol * 9 + q4 * 4;
            float4 v;
            v.x = ol[base + 0]; v.y = ol[base + 1];
            v.z = ol[base + 2]; v.w = ol[base + 3];
            const int bg = half * 16 + (bol >> 5);         // batch
            const int og = bol & 31;                       // out-channel
            *(float4*)(out + ((size_t)(bg * 32 + og)) * HW_
                           + h * 64 + w0 + q4 * 4) = v;
        }
        __syncthreads();
    }
}

extern "C" void kernel_launch(void* const* d_in, const int* in_sizes, int n_in,
                              void* d_out, int out_size, void* d_ws, size_t ws_size,
                              hipStream_t stream) {
    const float* x       = (const float*)d_in[0];
    const float* weights = (const float*)d_in[1];
    const float* bias    = (const float*)d_in[2];
    float* out           = (float*)d_out;
    (void)in_sizes; (void)n_in; (void)out_size; (void)d_ws; (void)ws_size;

    dim3 grid(512);     // 64 h x 8 w-groups, XCD-grouped by h&7
    dim3 block(512);    // 8 waves = 8 w-locations; 2 blocks/CU
    hipLaunchKernelGGL(xonv_kernel, grid, block, 0, stream, x, weights, bias, out);
}